// Round 1
// baseline (3417.476 us; speedup 1.0000x reference)
//
#include <hip/hip_runtime.h>

constexpr int DD = 128;

__device__ __forceinline__ void atomAddF(float* p, float v) {
  unsafeAtomicAdd(p, v);  // hardware global_atomic_add_f32 (plain atomicAdd = CAS loop)
}

// out[r][c] = (RELU?) sum_k in[r][k] * W[k][c] + b[c]
// W stored row-major [IC][OC]. Block = 256 threads.
template<int IC, int OC, bool RELU, int RPT>
__global__ void __launch_bounds__(256) linear_k(
    const float* __restrict__ in, const float* __restrict__ W,
    const float* __restrict__ bias, float* __restrict__ out, int nrows) {
  constexpr int GROUPS = 256 / OC;   // 1 (OC=256) or 2 (OC=128)
  constexpr int RBLK = RPT * GROUPS;
  __shared__ float xs[RBLK * IC];
  const int tid = threadIdx.x;
  const int c = tid % OC;
  const int g = tid / OC;
  const int rbase = blockIdx.x * RBLK;

  // stage RBLK input rows into LDS (float4)
  constexpr int NV = RBLK * IC / 4;
  const float4* in4 = reinterpret_cast<const float4*>(in);
  for (int idx = tid; idx < NV; idx += 256) {
    int r = idx / (IC / 4);
    int kk = idx % (IC / 4);
    int gr = rbase + r;
    float4 v = make_float4(0.f, 0.f, 0.f, 0.f);
    if (gr < nrows) v = in4[(size_t)gr * (IC / 4) + kk];
    reinterpret_cast<float4*>(xs)[idx] = v;
  }
  __syncthreads();

  float acc[RPT];
  float b = bias[c];
#pragma unroll
  for (int m = 0; m < RPT; m++) acc[m] = b;

#pragma unroll 4
  for (int k = 0; k < IC; k++) {
    float w = W[k * OC + c];               // coalesced, L1/L2-resident
#pragma unroll
    for (int m = 0; m < RPT; m++)
      acc[m] += xs[(g + m * GROUPS) * IC + k] * w;   // LDS broadcast
  }

#pragma unroll
  for (int m = 0; m < RPT; m++) {
    int gr = rbase + g + m * GROUPS;
    if (gr < nrows) {
      float v = acc[m];
      if (RELU) v = fmaxf(v, 0.f);
      out[(size_t)gr * OC + c] = v;
    }
  }
}

__global__ void __launch_bounds__(256) deg_init_k(float* deg, int n) {
  int i = blockIdx.x * 256 + threadIdx.x;
  if (i < n) deg[i] = 1.0f;  // self-loop contributes 1 to every node's src-degree
}

__global__ void __launch_bounds__(256) deg_accum_k(const int* __restrict__ src, int E,
                                                   float* __restrict__ deg) {
  int e = blockIdx.x * 256 + threadIdx.x;
  if (e < E) atomAddF(&deg[src[e]], 1.0f);
}

__global__ void __launch_bounds__(256) dinv_k(float* deg, int n) {
  int i = blockIdx.x * 256 + threadIdx.x;
  if (i < n) deg[i] = rsqrtf(deg[i]);  // deg >= 1 always (self-loops)
}

// msg = h[src] * dinv[src] * dinv[tgt]; out[tgt] += msg. e >= E encodes self-loop (e-E).
__global__ void __launch_bounds__(256) edge_scatter_k(
    const int* __restrict__ src, const int* __restrict__ tgt, int E, int n,
    const float* __restrict__ h, const float* __restrict__ dinv,
    float* __restrict__ out) {
  int e = blockIdx.x * 8 + (threadIdx.x >> 5);
  if (e >= E + n) return;
  int lane = threadIdx.x & 31;
  int s, t;
  if (e < E) { s = src[e]; t = tgt[e]; } else { s = e - E; t = s; }
  float nrm = dinv[s] * dinv[t];
  float4 v = reinterpret_cast<const float4*>(h + (size_t)s * DD)[lane];
  float* op = out + (size_t)t * DD + (size_t)lane * 4;
  atomAddF(op + 0, v.x * nrm);
  atomAddF(op + 1, v.y * nrm);
  atomAddF(op + 2, v.z * nrm);
  atomAddF(op + 3, v.w * nrm);
}

// frag_feats[a2f[a]] += x_atoms_new[a]
__global__ void __launch_bounds__(256) pool_k(
    const float* __restrict__ xan, const int* __restrict__ a2f, int n,
    float* __restrict__ ff) {
  int a = blockIdx.x * 8 + (threadIdx.x >> 5);
  if (a >= n) return;
  int lane = threadIdx.x & 31;
  int f = a2f[a];
  float4 v = reinterpret_cast<const float4*>(xan + (size_t)a * DD)[lane];
  float* op = ff + (size_t)f * DD + (size_t)lane * 4;
  atomAddF(op + 0, v.x);
  atomAddF(op + 1, v.y);
  atomAddF(op + 2, v.z);
  atomAddF(op + 3, v.w);
}

// frag_sum[ftgt[e]] += frag_feats[fsrc[e]]
__global__ void __launch_bounds__(256) frag_scatter_k(
    const int* __restrict__ fsrc, const int* __restrict__ ftgt, int FE,
    const float* __restrict__ ff, float* __restrict__ fs) {
  int e = blockIdx.x * 8 + (threadIdx.x >> 5);
  if (e >= FE) return;
  int lane = threadIdx.x & 31;
  int s = fsrc[e], t = ftgt[e];
  float4 v = reinterpret_cast<const float4*>(ff + (size_t)s * DD)[lane];
  float* op = fs + (size_t)t * DD + (size_t)lane * 4;
  atomAddF(op + 0, v.x);
  atomAddF(op + 1, v.y);
  atomAddF(op + 2, v.z);
  atomAddF(op + 3, v.w);
}

extern "C" void kernel_launch(void* const* d_in, const int* in_sizes, int n_in,
                              void* d_out, int out_size, void* d_ws, size_t ws_size,
                              hipStream_t stream) {
  const float* x_atoms  = (const float*)d_in[0];
  const int*   edge_index = (const int*)d_in[1];
  // d_in[2] edge_attr: UNUSED by the reference output (dead _e branch) — never read.
  const int*   frag_index = (const int*)d_in[3];
  // d_in[4] x_frags: values unused (only shape matters).
  const int*   a2f      = (const int*)d_in[5];
  const float* atom_w   = (const float*)d_in[6];
  const float* atom_b   = (const float*)d_in[7];
  // d_in[8], d_in[9] edge_w/edge_b: unused.
  const float* frag_w1  = (const float*)d_in[10];
  const float* frag_b1  = (const float*)d_in[11];
  const float* frag_w2  = (const float*)d_in[12];
  const float* frag_b2  = (const float*)d_in[13];

  const int N  = in_sizes[0] / DD;   // 100000
  const int E  = in_sizes[1] / 2;    // 1600000
  const int FE = in_sizes[3] / 2;    // 80000
  const int NF = in_sizes[4] / DD;   // 10000

  const int* esrc = edge_index;
  const int* etgt = edge_index + E;
  const int* fsrc = frag_index;
  const int* ftgt = frag_index + FE;

  float* out_atoms = (float*)d_out;                 // [N,128]
  float* out_frags = out_atoms + (size_t)N * DD;    // [NF,128]

  char* ws = (char*)d_ws;
  size_t off = 0;
  auto alloc = [&](size_t bytes) {
    void* p = ws + off;
    off += (bytes + 255) & ~(size_t)255;
    return p;
  };
  float* h   = (float*)alloc((size_t)N * DD * 4);        // 51.2 MB
  float* deg = (float*)alloc((size_t)N * 4);             // 0.4 MB (becomes dinv in-place)
  float* ff  = (float*)alloc((size_t)NF * DD * 4);       // 5.12 MB
  float* fs  = (float*)alloc((size_t)NF * DD * 4);       // 5.12 MB
  float* hid = (float*)alloc((size_t)NF * 2 * DD * 4);   // 10.24 MB

  // zero accumulators (harness poisons once, never re-poisons between replays)
  hipMemsetAsync(d_out, 0, (size_t)out_size * sizeof(float), stream);
  hipMemsetAsync(ff, 0, (size_t)NF * DD * sizeof(float), stream);
  hipMemsetAsync(fs, 0, (size_t)NF * DD * sizeof(float), stream);

  deg_init_k<<<(N + 255) / 256, 256, 0, stream>>>(deg, N);
  deg_accum_k<<<(E + 255) / 256, 256, 0, stream>>>(esrc, E, deg);
  dinv_k<<<(N + 255) / 256, 256, 0, stream>>>(deg, N);

  // h = x_atoms @ atom_w + atom_b
  linear_k<128, 128, false, 32><<<(N + 63) / 64, 256, 0, stream>>>(x_atoms, atom_w, atom_b, h, N);

  int tot = E + N;
  edge_scatter_k<<<(tot + 7) / 8, 256, 0, stream>>>(esrc, etgt, E, N, h, deg, out_atoms);

  pool_k<<<(N + 7) / 8, 256, 0, stream>>>(out_atoms, a2f, N, ff);
  frag_scatter_k<<<(FE + 7) / 8, 256, 0, stream>>>(fsrc, ftgt, FE, ff, fs);

  // MLP: hid = relu(fs @ w1 + b1); out_frags = hid @ w2 + b2
  linear_k<128, 256, true, 32><<<(NF + 31) / 32, 256, 0, stream>>>(fs, frag_w1, frag_b1, hid, NF);
  linear_k<256, 128, false, 16><<<(NF + 31) / 32, 256, 0, stream>>>(hid, frag_w2, frag_b2, out_frags, NF);
}

// Round 2
// 638.488 us; speedup vs baseline: 5.3525x; 5.3525x over previous
//
#include <hip/hip_runtime.h>

constexpr int DD = 128;

// ======================= Linear (f32, LDS-staged) =======================
// out[r][c] = (RELU?) sum_k in[r][k] * W[k][c] + b[c] ; W row-major [IC][OC]
template<int IC, int OC, bool RELU, int RPT>
__global__ void __launch_bounds__(256) linear_k(
    const float* __restrict__ in, const float* __restrict__ W,
    const float* __restrict__ bias, float* __restrict__ out, int nrows) {
  constexpr int GROUPS = 256 / OC;
  constexpr int RBLK = RPT * GROUPS;
  __shared__ float xs[RBLK * IC];
  const int tid = threadIdx.x;
  const int c = tid % OC;
  const int g = tid / OC;
  const int rbase = blockIdx.x * RBLK;

  constexpr int NV = RBLK * IC / 4;
  const float4* in4 = reinterpret_cast<const float4*>(in);
  for (int idx = tid; idx < NV; idx += 256) {
    int r = idx / (IC / 4);
    int kk = idx % (IC / 4);
    int gr = rbase + r;
    float4 v = make_float4(0.f, 0.f, 0.f, 0.f);
    if (gr < nrows) v = in4[(size_t)gr * (IC / 4) + kk];
    reinterpret_cast<float4*>(xs)[idx] = v;
  }
  __syncthreads();

  float acc[RPT];
  float b = bias[c];
#pragma unroll
  for (int m = 0; m < RPT; m++) acc[m] = b;

#pragma unroll 4
  for (int k = 0; k < IC; k++) {
    float w = W[k * OC + c];
#pragma unroll
    for (int m = 0; m < RPT; m++)
      acc[m] += xs[(g + m * GROUPS) * IC + k] * w;
  }

#pragma unroll
  for (int m = 0; m < RPT; m++) {
    int gr = rbase + g + m * GROUPS;
    if (gr < nrows) {
      float v = acc[m];
      if (RELU) v = fmaxf(v, 0.f);
      out[(size_t)gr * OC + c] = v;
    }
  }
}

// ======================= CSR build =======================
__global__ void __launch_bounds__(256) count2_k(const int* __restrict__ src,
                                                const int* __restrict__ tgt, int E,
                                                int* __restrict__ cnt_src,
                                                int* __restrict__ cnt_tgt) {
  int e = blockIdx.x * 256 + threadIdx.x;
  if (e < E) {
    atomicAdd(&cnt_src[src[e]], 1);
    atomicAdd(&cnt_tgt[tgt[e]], 1);
  }
}

__global__ void __launch_bounds__(256) count1_k(const int* __restrict__ idx, int n,
                                                int* __restrict__ cnt) {
  int i = blockIdx.x * 256 + threadIdx.x;
  if (i < n) atomicAdd(&cnt[idx[i]], 1);
}

__global__ void __launch_bounds__(256) dinv_k(const int* __restrict__ cnt_src, int n,
                                              float* __restrict__ dinv) {
  int i = blockIdx.x * 256 + threadIdx.x;
  if (i < n) dinv[i] = rsqrtf((float)(cnt_src[i] + 1));  // +1 self-loop
}

constexpr int SCAN_C = 1024;  // elements per scan block

__global__ void __launch_bounds__(256) scan_bsum_k(const int* __restrict__ in, int n,
                                                   int* __restrict__ bsums) {
  __shared__ int s[256];
  int t = threadIdx.x;
  int base = blockIdx.x * SCAN_C;
  int v = 0;
  for (int i = t; i < SCAN_C; i += 256) {
    int g = base + i;
    if (g < n) v += in[g];
  }
  s[t] = v;
  __syncthreads();
  for (int d = 128; d > 0; d >>= 1) {
    if (t < d) s[t] += s[t + d];
    __syncthreads();
  }
  if (t == 0) bsums[blockIdx.x] = s[0];
}

__global__ void __launch_bounds__(1024) scan_small_k(int* __restrict__ bsums, int nb) {
  __shared__ int s[1024];
  int t = threadIdx.x;
  int v = (t < nb) ? bsums[t] : 0;
  s[t] = v;
  __syncthreads();
  for (int d = 1; d < 1024; d <<= 1) {
    int u = (t >= d) ? s[t - d] : 0;
    __syncthreads();
    s[t] += u;
    __syncthreads();
  }
  if (t < nb) bsums[t] = s[t] - v;  // exclusive
}

__global__ void __launch_bounds__(256) scan_final_k(const int* __restrict__ in, int n,
                                                    const int* __restrict__ bsums,
                                                    int* __restrict__ off,
                                                    int* __restrict__ cur) {
  __shared__ int s[256];
  int t = threadIdx.x;
  int base = blockIdx.x * SCAN_C + t * 4;
  int a0 = (base + 0 < n) ? in[base + 0] : 0;
  int a1 = (base + 1 < n) ? in[base + 1] : 0;
  int a2 = (base + 2 < n) ? in[base + 2] : 0;
  int a3 = (base + 3 < n) ? in[base + 3] : 0;
  int tot = a0 + a1 + a2 + a3;
  s[t] = tot;
  __syncthreads();
  for (int d = 1; d < 256; d <<= 1) {
    int u = (t >= d) ? s[t - d] : 0;
    __syncthreads();
    s[t] += u;
    __syncthreads();
  }
  int pre = s[t] - tot + bsums[blockIdx.x];
  int e0 = pre, e1 = pre + a0, e2 = e1 + a1, e3 = e2 + a2;
  if (base + 0 < n) { off[base + 0] = e0; cur[base + 0] = e0; }
  if (base + 1 < n) { off[base + 1] = e1; cur[base + 1] = e1; }
  if (base + 2 < n) { off[base + 2] = e2; cur[base + 2] = e2; }
  if (base + 3 < n) { off[base + 3] = e3; cur[base + 3] = e3; }
}

// scatter edge payload into CSR slots: csr_val[pos] = val[e] grouped by key[e]
__global__ void __launch_bounds__(256) fill_edges_k(const int* __restrict__ val,
                                                    const int* __restrict__ key, int E,
                                                    int* __restrict__ cur,
                                                    int* __restrict__ csr_val) {
  int e = blockIdx.x * 256 + threadIdx.x;
  if (e < E) {
    int pos = atomicAdd(&cur[key[e]], 1);
    csr_val[pos] = val[e];
  }
}

// group element ids by idx[i]
__global__ void __launch_bounds__(256) fill_idx_k(const int* __restrict__ idx, int n,
                                                  int* __restrict__ cur,
                                                  int* __restrict__ ids) {
  int i = blockIdx.x * 256 + threadIdx.x;
  if (i < n) {
    int pos = atomicAdd(&cur[idx[i]], 1);
    ids[pos] = i;
  }
}

// ======================= Gather phases =======================
// out[t] = h[t]*dinv[t]^2 + sum_{s in csr} h[s]*dinv[s]*dinv[t]
__global__ void __launch_bounds__(256) edge_gather_k(
    const int* __restrict__ off, const int* __restrict__ cnt,
    const int* __restrict__ csr_src, const float* __restrict__ h,
    const float* __restrict__ dinv, float* __restrict__ out, int n) {
  int tn = blockIdx.x * 8 + (threadIdx.x >> 5);
  if (tn >= n) return;
  int lane = threadIdx.x & 31;
  const float4* h4 = reinterpret_cast<const float4*>(h);
  float dt = dinv[tn];
  float4 hv = h4[(size_t)tn * 32 + lane];
  float sw = dt * dt;
  float ax = hv.x * sw, ay = hv.y * sw, az = hv.z * sw, aw = hv.w * sw;
  int s0 = off[tn], c = cnt[tn];
  for (int i = 0; i < c; i++) {
    int s = csr_src[s0 + i];
    float nrm = dinv[s] * dt;
    float4 v = h4[(size_t)s * 32 + lane];
    ax += v.x * nrm; ay += v.y * nrm; az += v.z * nrm; aw += v.w * nrm;
  }
  reinterpret_cast<float4*>(out)[(size_t)tn * 32 + lane] = make_float4(ax, ay, az, aw);
}

// dst[f] = sum_{a in group f} src_rows[a]
__global__ void __launch_bounds__(256) seg_gather_k(
    const int* __restrict__ off, const int* __restrict__ cnt,
    const int* __restrict__ ids, const float* __restrict__ src_rows,
    float* __restrict__ dst, int n) {
  int f = blockIdx.x * 8 + (threadIdx.x >> 5);
  if (f >= n) return;
  int lane = threadIdx.x & 31;
  const float4* s4 = reinterpret_cast<const float4*>(src_rows);
  float ax = 0.f, ay = 0.f, az = 0.f, aw = 0.f;
  int s0 = off[f], c = cnt[f];
  for (int i = 0; i < c; i++) {
    int a = ids[s0 + i];
    float4 v = s4[(size_t)a * 32 + lane];
    ax += v.x; ay += v.y; az += v.z; aw += v.w;
  }
  reinterpret_cast<float4*>(dst)[(size_t)f * 32 + lane] = make_float4(ax, ay, az, aw);
}

// ======================= Launch =======================
extern "C" void kernel_launch(void* const* d_in, const int* in_sizes, int n_in,
                              void* d_out, int out_size, void* d_ws, size_t ws_size,
                              hipStream_t stream) {
  const float* x_atoms    = (const float*)d_in[0];
  const int*   edge_index = (const int*)d_in[1];
  // d_in[2] edge_attr: dead in reference — never read.
  const int*   frag_index = (const int*)d_in[3];
  // d_in[4] x_frags: values unused.
  const int*   a2f     = (const int*)d_in[5];
  const float* atom_w  = (const float*)d_in[6];
  const float* atom_b  = (const float*)d_in[7];
  // d_in[8..9] edge_w/edge_b: unused.
  const float* frag_w1 = (const float*)d_in[10];
  const float* frag_b1 = (const float*)d_in[11];
  const float* frag_w2 = (const float*)d_in[12];
  const float* frag_b2 = (const float*)d_in[13];

  const int N  = in_sizes[0] / DD;   // 100000
  const int E  = in_sizes[1] / 2;    // 1600000
  const int FE = in_sizes[3] / 2;    // 80000
  const int NF = in_sizes[4] / DD;   // 10000

  const int* esrc = edge_index;
  const int* etgt = edge_index + E;
  const int* fsrc = frag_index;
  const int* ftgt = frag_index + FE;

  float* out_atoms = (float*)d_out;
  float* out_frags = out_atoms + (size_t)N * DD;

  char* ws = (char*)d_ws;
  size_t off_b = 0;
  auto alloc = [&](size_t bytes) {
    void* p = ws + off_b;
    off_b += (bytes + 255) & ~(size_t)255;
    return p;
  };
  float* h       = (float*)alloc((size_t)N * DD * 4);   // 51.2 MB
  float* dinv    = (float*)alloc((size_t)N * 4);
  int*   cnt2    = (int*)alloc((size_t)2 * N * 4);      // cnt_src | cnt_tgt
  int*   cnt_src = cnt2;
  int*   cnt_tgt = cnt2 + N;
  int*   off_tgt = (int*)alloc((size_t)N * 4);
  int*   cur_tgt = (int*)alloc((size_t)N * 4);
  int*   csr_src = (int*)alloc((size_t)E * 4);          // 6.4 MB
  int*   cntf2   = (int*)alloc((size_t)2 * NF * 4);     // cnt_a2f | cnt_fe
  int*   cnt_a2f = cntf2;
  int*   cnt_fe  = cntf2 + NF;
  int*   off_a2f = (int*)alloc((size_t)NF * 4);
  int*   cur_a2f = (int*)alloc((size_t)NF * 4);
  int*   aids    = (int*)alloc((size_t)N * 4);
  int*   off_fe  = (int*)alloc((size_t)NF * 4);
  int*   cur_fe  = (int*)alloc((size_t)NF * 4);
  int*   csr_fs  = (int*)alloc((size_t)FE * 4);
  int*   bsums   = (int*)alloc(1024 * 4);
  float* ff      = (float*)alloc((size_t)NF * DD * 4);
  float* fs      = (float*)alloc((size_t)NF * DD * 4);
  float* hid     = (float*)alloc((size_t)NF * 2 * DD * 4);

  // zero only the count arrays (all other buffers are fully overwritten)
  hipMemsetAsync(cnt2, 0, (size_t)2 * N * 4, stream);
  hipMemsetAsync(cntf2, 0, (size_t)2 * NF * 4, stream);

  // ---- counts ----
  count2_k<<<(E + 255) / 256, 256, 0, stream>>>(esrc, etgt, E, cnt_src, cnt_tgt);
  count1_k<<<(N + 255) / 256, 256, 0, stream>>>(a2f, N, cnt_a2f);
  count1_k<<<(FE + 255) / 256, 256, 0, stream>>>(ftgt, FE, cnt_fe);
  dinv_k<<<(N + 255) / 256, 256, 0, stream>>>(cnt_src, N, dinv);

  // ---- scans (exclusive) ----
  int nb1 = (N + SCAN_C - 1) / SCAN_C;    // 98
  scan_bsum_k<<<nb1, 256, 0, stream>>>(cnt_tgt, N, bsums);
  scan_small_k<<<1, 1024, 0, stream>>>(bsums, nb1);
  scan_final_k<<<nb1, 256, 0, stream>>>(cnt_tgt, N, bsums, off_tgt, cur_tgt);

  int nb2 = (NF + SCAN_C - 1) / SCAN_C;   // 10
  scan_bsum_k<<<nb2, 256, 0, stream>>>(cnt_a2f, NF, bsums);
  scan_small_k<<<1, 1024, 0, stream>>>(bsums, nb2);
  scan_final_k<<<nb2, 256, 0, stream>>>(cnt_a2f, NF, bsums, off_a2f, cur_a2f);

  scan_bsum_k<<<nb2, 256, 0, stream>>>(cnt_fe, NF, bsums);
  scan_small_k<<<1, 1024, 0, stream>>>(bsums, nb2);
  scan_final_k<<<nb2, 256, 0, stream>>>(cnt_fe, NF, bsums, off_fe, cur_fe);

  // ---- fills ----
  fill_edges_k<<<(E + 255) / 256, 256, 0, stream>>>(esrc, etgt, E, cur_tgt, csr_src);
  fill_idx_k<<<(N + 255) / 256, 256, 0, stream>>>(a2f, N, cur_a2f, aids);
  fill_edges_k<<<(FE + 255) / 256, 256, 0, stream>>>(fsrc, ftgt, FE, cur_fe, csr_fs);

  // ---- h = x_atoms @ atom_w + atom_b ----
  linear_k<128, 128, false, 32><<<(N + 63) / 64, 256, 0, stream>>>(x_atoms, atom_w, atom_b, h, N);

  // ---- gathers ----
  edge_gather_k<<<(N + 7) / 8, 256, 0, stream>>>(off_tgt, cnt_tgt, csr_src, h, dinv, out_atoms, N);
  seg_gather_k<<<(NF + 7) / 8, 256, 0, stream>>>(off_a2f, cnt_a2f, aids, out_atoms, ff, NF);
  seg_gather_k<<<(NF + 7) / 8, 256, 0, stream>>>(off_fe, cnt_fe, csr_fs, ff, fs, NF);

  // ---- MLP ----
  linear_k<128, 256, true, 32><<<(NF + 31) / 32, 256, 0, stream>>>(fs, frag_w1, frag_b1, hid, NF);
  linear_k<256, 128, false, 16><<<(NF + 31) / 32, 256, 0, stream>>>(hid, frag_w2, frag_b2, out_frags, NF);
}

// Round 3
// 571.046 us; speedup vs baseline: 5.9846x; 1.1181x over previous
//
#include <hip/hip_runtime.h>

constexpr int DD = 128;

__device__ __forceinline__ float bf2f(unsigned short u) {
  union { unsigned int i; float f; } c;
  c.i = ((unsigned int)u) << 16;
  return c.f;
}
__device__ __forceinline__ unsigned short f2bf(float f) {
  union { float f; unsigned int i; } c;
  c.f = f;
  unsigned int x = c.i;
  x += 0x7fff + ((x >> 16) & 1);  // RNE
  return (unsigned short)(x >> 16);
}

// ================= Linear f32 (generic, for the frag MLP) =================
template<int IC, int OC, bool RELU, int RPT>
__global__ void __launch_bounds__(256) linear_k(
    const float* __restrict__ in, const float* __restrict__ W,
    const float* __restrict__ bias, float* __restrict__ out, int nrows) {
  constexpr int GROUPS = 256 / OC;
  constexpr int RBLK = RPT * GROUPS;
  __shared__ float xs[RBLK * IC];
  const int tid = threadIdx.x;
  const int c = tid % OC;
  const int g = tid / OC;
  const int rbase = blockIdx.x * RBLK;

  constexpr int NV = RBLK * IC / 4;
  const float4* in4 = reinterpret_cast<const float4*>(in);
  for (int idx = tid; idx < NV; idx += 256) {
    int r = idx / (IC / 4);
    int kk = idx % (IC / 4);
    int gr = rbase + r;
    float4 v = make_float4(0.f, 0.f, 0.f, 0.f);
    if (gr < nrows) v = in4[(size_t)gr * (IC / 4) + kk];
    reinterpret_cast<float4*>(xs)[idx] = v;
  }
  __syncthreads();

  float acc[RPT];
  float b = bias[c];
#pragma unroll
  for (int m = 0; m < RPT; m++) acc[m] = b;

#pragma unroll 4
  for (int k = 0; k < IC; k++) {
    float w = W[k * OC + c];
#pragma unroll
    for (int m = 0; m < RPT; m++)
      acc[m] += xs[(g + m * GROUPS) * IC + k] * w;
  }

#pragma unroll
  for (int m = 0; m < RPT; m++) {
    int gr = rbase + g + m * GROUPS;
    if (gr < nrows) {
      float v = acc[m];
      if (RELU) v = fmaxf(v, 0.f);
      out[(size_t)gr * OC + c] = v;
    }
  }
}

// ====== h' = (x @ W + b) * dinv[row], output bf16 (128 -> 128) ======
__global__ void __launch_bounds__(256) linear_h_k(
    const float* __restrict__ in, const float* __restrict__ W,
    const float* __restrict__ bias, const float* __restrict__ dinv,
    unsigned short* __restrict__ out, int nrows) {
  constexpr int RPT = 32, GROUPS = 2, RBLK = 64, IC = 128, OC = 128;
  __shared__ float xs[RBLK * IC];
  const int tid = threadIdx.x;
  const int c = tid % OC;
  const int g = tid / OC;
  const int rbase = blockIdx.x * RBLK;

  constexpr int NV = RBLK * IC / 4;
  const float4* in4 = reinterpret_cast<const float4*>(in);
  for (int idx = tid; idx < NV; idx += 256) {
    int r = idx / (IC / 4);
    int kk = idx % (IC / 4);
    int gr = rbase + r;
    float4 v = make_float4(0.f, 0.f, 0.f, 0.f);
    if (gr < nrows) v = in4[(size_t)gr * (IC / 4) + kk];
    reinterpret_cast<float4*>(xs)[idx] = v;
  }
  __syncthreads();

  float acc[RPT];
  float b = bias[c];
#pragma unroll
  for (int m = 0; m < RPT; m++) acc[m] = b;

#pragma unroll 4
  for (int k = 0; k < IC; k++) {
    float w = W[k * OC + c];
#pragma unroll
    for (int m = 0; m < RPT; m++)
      acc[m] += xs[(g + m * GROUPS) * IC + k] * w;
  }

#pragma unroll
  for (int m = 0; m < RPT; m++) {
    int gr = rbase + g + m * GROUPS;
    if (gr < nrows)
      out[(size_t)gr * OC + c] = f2bf(acc[m] * dinv[gr]);
  }
}

// ================= counts =================
__global__ void __launch_bounds__(256) count2_k(const int* __restrict__ src,
                                                const int* __restrict__ tgt, int E,
                                                int* __restrict__ cnt_src,
                                                int* __restrict__ cnt_tgt) {
  int e = blockIdx.x * 256 + threadIdx.x;
  if (e < E) {
    atomicAdd(&cnt_src[src[e]], 1);
    atomicAdd(&cnt_tgt[tgt[e]], 1);
  }
}

// segment 0: count a2f over N; segment 1: count ftgt over FE; segment 2: dinv over N
__global__ void __launch_bounds__(256) count_misc_k(
    const int* __restrict__ a2f, int N, const int* __restrict__ ftgt, int FE,
    const int* __restrict__ cnt_src, int* __restrict__ cnt_a2f,
    int* __restrict__ cnt_fe, float* __restrict__ dinv) {
  int i = blockIdx.x * 256 + threadIdx.x;
  if (i < N) {
    atomicAdd(&cnt_a2f[a2f[i]], 1);
  } else if (i < N + FE) {
    atomicAdd(&cnt_fe[ftgt[i - N]], 1);
  } else if (i < 2 * N + FE) {
    int j = i - N - FE;
    dinv[j] = rsqrtf((float)(cnt_src[j] + 1));  // +1 self-loop
  }
}

// ================= scans =================
constexpr int SCAN_C = 1024;

__global__ void __launch_bounds__(256) scan_bsum_k(const int* __restrict__ in, int n,
                                                   int* __restrict__ bsums) {
  __shared__ int s[256];
  int t = threadIdx.x;
  int base = blockIdx.x * SCAN_C;
  int v = 0;
  for (int i = t; i < SCAN_C; i += 256) {
    int g = base + i;
    if (g < n) v += in[g];
  }
  s[t] = v;
  __syncthreads();
  for (int d = 128; d > 0; d >>= 1) {
    if (t < d) s[t] += s[t + d];
    __syncthreads();
  }
  if (t == 0) bsums[blockIdx.x] = s[0];
}

__global__ void __launch_bounds__(1024) scan_small_k(int* __restrict__ bsums, int nb) {
  __shared__ int s[1024];
  int t = threadIdx.x;
  int v = (t < nb) ? bsums[t] : 0;
  s[t] = v;
  __syncthreads();
  for (int d = 1; d < 1024; d <<= 1) {
    int u = (t >= d) ? s[t - d] : 0;
    __syncthreads();
    s[t] += u;
    __syncthreads();
  }
  if (t < nb) bsums[t] = s[t] - v;  // exclusive
}

__global__ void __launch_bounds__(256) scan_final_k(const int* __restrict__ in, int n,
                                                    const int* __restrict__ bsums,
                                                    int* __restrict__ off,
                                                    int* __restrict__ cur) {
  __shared__ int s[256];
  int t = threadIdx.x;
  int base = blockIdx.x * SCAN_C + t * 4;
  int a0 = (base + 0 < n) ? in[base + 0] : 0;
  int a1 = (base + 1 < n) ? in[base + 1] : 0;
  int a2 = (base + 2 < n) ? in[base + 2] : 0;
  int a3 = (base + 3 < n) ? in[base + 3] : 0;
  int tot = a0 + a1 + a2 + a3;
  s[t] = tot;
  __syncthreads();
  for (int d = 1; d < 256; d <<= 1) {
    int u = (t >= d) ? s[t - d] : 0;
    __syncthreads();
    s[t] += u;
    __syncthreads();
  }
  int pre = s[t] - tot + bsums[blockIdx.x];
  int e0 = pre, e1 = pre + a0, e2 = e1 + a1, e3 = e2 + a2;
  if (base + 0 < n) { off[base + 0] = e0; cur[base + 0] = e0; }
  if (base + 1 < n) { off[base + 1] = e1; cur[base + 1] = e1; }
  if (base + 2 < n) { off[base + 2] = e2; cur[base + 2] = e2; }
  if (base + 3 < n) { off[base + 3] = e3; cur[base + 3] = e3; }
}

// single-block scan for small arrays; blockIdx selects which job
__global__ void __launch_bounds__(1024) scan2_k(
    const int* __restrict__ in0, int n0, int* __restrict__ off0, int* __restrict__ cur0,
    const int* __restrict__ in1, int n1, int* __restrict__ off1, int* __restrict__ cur1) {
  __shared__ int s[1024];
  const int* in = blockIdx.x == 0 ? in0 : in1;
  int n = blockIdx.x == 0 ? n0 : n1;
  int* off = blockIdx.x == 0 ? off0 : off1;
  int* cur = blockIdx.x == 0 ? cur0 : cur1;
  int t = threadIdx.x;
  int carry = 0;
  for (int base = 0; base < n; base += 1024) {
    int v = (base + t < n) ? in[base + t] : 0;
    __syncthreads();
    s[t] = v;
    __syncthreads();
    for (int d = 1; d < 1024; d <<= 1) {
      int u = (t >= d) ? s[t - d] : 0;
      __syncthreads();
      s[t] += u;
      __syncthreads();
    }
    int tot = s[1023];
    int excl = s[t] - v + carry;
    if (base + t < n) { off[base + t] = excl; cur[base + t] = excl; }
    carry += tot;
  }
}

// ================= fills =================
__global__ void __launch_bounds__(256) fill_edges_k(const int* __restrict__ val,
                                                    const int* __restrict__ key, int E,
                                                    int* __restrict__ cur,
                                                    int* __restrict__ csr_val) {
  int e = blockIdx.x * 256 + threadIdx.x;
  if (e < E) {
    int pos = atomicAdd(&cur[key[e]], 1);
    csr_val[pos] = val[e];
  }
}

// segment 0: group atom ids by a2f; segment 1: group fsrc by ftgt
__global__ void __launch_bounds__(256) fill_misc_k(
    const int* __restrict__ a2f, int N, int* __restrict__ cur_a2f, int* __restrict__ aids,
    const int* __restrict__ fsrc, const int* __restrict__ ftgt, int FE,
    int* __restrict__ cur_fe, int* __restrict__ csr_fs) {
  int i = blockIdx.x * 256 + threadIdx.x;
  if (i < N) {
    int pos = atomicAdd(&cur_a2f[a2f[i]], 1);
    aids[pos] = i;
  } else if (i < N + FE) {
    int e = i - N;
    int pos = atomicAdd(&cur_fe[ftgt[e]], 1);
    csr_fs[pos] = fsrc[e];
  }
}

// ================= gathers =================
// out[t] = dinv[t] * (h'[t] + sum_{s in csr(t)} h'[s]) ; h' bf16
__global__ void __launch_bounds__(256) edge_gather_k(
    const int* __restrict__ off, const int* __restrict__ cnt,
    const int* __restrict__ csr_src, const unsigned short* __restrict__ h,
    const float* __restrict__ dinv, float* __restrict__ out, int n) {
  int tn = blockIdx.x * 8 + (threadIdx.x >> 5);
  if (tn >= n) return;
  int lane = threadIdx.x & 31;
  const ushort4* h4 = reinterpret_cast<const ushort4*>(h);  // 4 bf16 per lane, 32 lanes/row
  ushort4 hv = h4[(size_t)tn * 32 + lane];
  float ax = bf2f(hv.x), ay = bf2f(hv.y), az = bf2f(hv.z), aw = bf2f(hv.w);
  int s0 = off[tn], c = cnt[tn];
  int i = 0;
  for (; i + 2 <= c; i += 2) {
    int s1 = csr_src[s0 + i];
    int s2 = csr_src[s0 + i + 1];
    ushort4 v1 = h4[(size_t)s1 * 32 + lane];
    ushort4 v2 = h4[(size_t)s2 * 32 + lane];
    ax += bf2f(v1.x) + bf2f(v2.x);
    ay += bf2f(v1.y) + bf2f(v2.y);
    az += bf2f(v1.z) + bf2f(v2.z);
    aw += bf2f(v1.w) + bf2f(v2.w);
  }
  if (i < c) {
    int s1 = csr_src[s0 + i];
    ushort4 v1 = h4[(size_t)s1 * 32 + lane];
    ax += bf2f(v1.x); ay += bf2f(v1.y); az += bf2f(v1.z); aw += bf2f(v1.w);
  }
  float dt = dinv[tn];
  reinterpret_cast<float4*>(out)[(size_t)tn * 32 + lane] =
      make_float4(ax * dt, ay * dt, az * dt, aw * dt);
}

// dst[f] = sum_{a in group f} src_rows[a]  (f32 rows)
__global__ void __launch_bounds__(256) seg_gather_k(
    const int* __restrict__ off, const int* __restrict__ cnt,
    const int* __restrict__ ids, const float* __restrict__ src_rows,
    float* __restrict__ dst, int n) {
  int f = blockIdx.x * 8 + (threadIdx.x >> 5);
  if (f >= n) return;
  int lane = threadIdx.x & 31;
  const float4* s4 = reinterpret_cast<const float4*>(src_rows);
  float ax = 0.f, ay = 0.f, az = 0.f, aw = 0.f;
  int s0 = off[f], c = cnt[f];
  for (int i = 0; i < c; i++) {
    int a = ids[s0 + i];
    float4 v = s4[(size_t)a * 32 + lane];
    ax += v.x; ay += v.y; az += v.z; aw += v.w;
  }
  reinterpret_cast<float4*>(dst)[(size_t)f * 32 + lane] = make_float4(ax, ay, az, aw);
}

// ================= launch =================
extern "C" void kernel_launch(void* const* d_in, const int* in_sizes, int n_in,
                              void* d_out, int out_size, void* d_ws, size_t ws_size,
                              hipStream_t stream) {
  const float* x_atoms    = (const float*)d_in[0];
  const int*   edge_index = (const int*)d_in[1];
  // d_in[2] edge_attr: dead in reference — never read.
  const int*   frag_index = (const int*)d_in[3];
  // d_in[4] x_frags: values unused.
  const int*   a2f     = (const int*)d_in[5];
  const float* atom_w  = (const float*)d_in[6];
  const float* atom_b  = (const float*)d_in[7];
  // d_in[8..9] edge_w/edge_b: unused.
  const float* frag_w1 = (const float*)d_in[10];
  const float* frag_b1 = (const float*)d_in[11];
  const float* frag_w2 = (const float*)d_in[12];
  const float* frag_b2 = (const float*)d_in[13];

  const int N  = in_sizes[0] / DD;   // 100000
  const int E  = in_sizes[1] / 2;    // 1600000
  const int FE = in_sizes[3] / 2;    // 80000
  const int NF = in_sizes[4] / DD;   // 10000

  const int* esrc = edge_index;
  const int* etgt = edge_index + E;
  const int* fsrc = frag_index;
  const int* ftgt = frag_index + FE;

  float* out_atoms = (float*)d_out;
  float* out_frags = out_atoms + (size_t)N * DD;

  char* ws = (char*)d_ws;
  size_t off_b = 0;
  auto alloc = [&](size_t bytes) {
    void* p = ws + off_b;
    off_b += (bytes + 255) & ~(size_t)255;
    return p;
  };
  unsigned short* h = (unsigned short*)alloc((size_t)N * DD * 2);  // 25.6 MB bf16
  float* dinv    = (float*)alloc((size_t)N * 4);
  int*   cnts    = (int*)alloc(((size_t)2 * N + 2 * NF) * 4);  // one zeroed block
  int*   cnt_src = cnts;
  int*   cnt_tgt = cnts + N;
  int*   cnt_a2f = cnts + 2 * N;
  int*   cnt_fe  = cnts + 2 * N + NF;
  int*   off_tgt = (int*)alloc((size_t)N * 4);
  int*   cur_tgt = (int*)alloc((size_t)N * 4);
  int*   csr_src = (int*)alloc((size_t)E * 4);
  int*   off_a2f = (int*)alloc((size_t)NF * 4);
  int*   cur_a2f = (int*)alloc((size_t)NF * 4);
  int*   aids    = (int*)alloc((size_t)N * 4);
  int*   off_fe  = (int*)alloc((size_t)NF * 4);
  int*   cur_fe  = (int*)alloc((size_t)NF * 4);
  int*   csr_fs  = (int*)alloc((size_t)FE * 4);
  int*   bsums   = (int*)alloc(1024 * 4);
  float* ff      = (float*)alloc((size_t)NF * DD * 4);
  float* fs      = (float*)alloc((size_t)NF * DD * 4);
  float* hid     = (float*)alloc((size_t)NF * 2 * DD * 4);

  hipMemsetAsync(cnts, 0, ((size_t)2 * N + 2 * NF) * 4, stream);

  // counts (+ dinv fused)
  count2_k<<<(E + 255) / 256, 256, 0, stream>>>(esrc, etgt, E, cnt_src, cnt_tgt);
  count_misc_k<<<(2 * N + FE + 255) / 256, 256, 0, stream>>>(
      a2f, N, ftgt, FE, cnt_src, cnt_a2f, cnt_fe, dinv);

  // scans
  int nb1 = (N + SCAN_C - 1) / SCAN_C;
  scan_bsum_k<<<nb1, 256, 0, stream>>>(cnt_tgt, N, bsums);
  scan_small_k<<<1, 1024, 0, stream>>>(bsums, nb1);
  scan_final_k<<<nb1, 256, 0, stream>>>(cnt_tgt, N, bsums, off_tgt, cur_tgt);
  scan2_k<<<2, 1024, 0, stream>>>(cnt_a2f, NF, off_a2f, cur_a2f,
                                  cnt_fe, NF, off_fe, cur_fe);

  // fills
  fill_edges_k<<<(E + 255) / 256, 256, 0, stream>>>(esrc, etgt, E, cur_tgt, csr_src);
  fill_misc_k<<<(N + FE + 255) / 256, 256, 0, stream>>>(
      a2f, N, cur_a2f, aids, fsrc, ftgt, FE, cur_fe, csr_fs);

  // h' = (x @ W + b) * dinv  (bf16)
  linear_h_k<<<(N + 63) / 64, 256, 0, stream>>>(x_atoms, atom_w, atom_b, dinv, h, N);

  // gathers
  edge_gather_k<<<(N + 7) / 8, 256, 0, stream>>>(off_tgt, cnt_tgt, csr_src, h, dinv, out_atoms, N);
  seg_gather_k<<<(NF + 7) / 8, 256, 0, stream>>>(off_a2f, cnt_a2f, aids, out_atoms, ff, NF);
  seg_gather_k<<<(NF + 7) / 8, 256, 0, stream>>>(off_fe, cnt_fe, csr_fs, ff, fs, NF);

  // MLP (f32)
  linear_k<128, 256, true, 32><<<(NF + 31) / 32, 256, 0, stream>>>(fs, frag_w1, frag_b1, hid, NF);
  linear_k<256, 128, false, 16><<<(NF + 31) / 32, 256, 0, stream>>>(hid, frag_w2, frag_b2, out_frags, NF);
}

// Round 4
// 396.916 us; speedup vs baseline: 8.6101x; 1.4387x over previous
//
#include <hip/hip_runtime.h>

constexpr int DD = 128;

typedef __attribute__((ext_vector_type(8))) short short8_t;   // 8 bf16 = 4 VGPR
typedef __attribute__((ext_vector_type(4))) float f32x4;

__device__ __forceinline__ float bf2f(unsigned short u) {
  union { unsigned int i; float f; } c;
  c.i = ((unsigned int)u) << 16;
  return c.f;
}
__device__ __forceinline__ unsigned short f2bf(float f) {
  union { float f; unsigned int i; } c;
  c.f = f;
  unsigned int x = c.i;
  x += 0x7fff + ((x >> 16) & 1);  // RNE
  return (unsigned short)(x >> 16);
}

// ================= MFMA GEMM: h' = bf16((x @ W + b) * dinv[row]) =================
// M=nrows, N=128, K=128. Block 256 thr = 4 waves; block tile 128 rows.
// Wave computes 32 rows x 128 cols = 2 row-subtiles x 8 col-tiles of 16x16x32 MFMA.
// W staged in LDS as Wt[col][k] bf16, XOR-swizzled; x read direct global->reg.
__global__ void __launch_bounds__(256) mfma_h_k(
    const float* __restrict__ x, const float* __restrict__ W,
    const float* __restrict__ bias, const float* __restrict__ dinv,
    unsigned short* __restrict__ out, int nrows) {
  __shared__ unsigned int wt[8192];  // 128 cols x 64 dwords (128 bf16 k), swizzled

  const int tid = threadIdx.x;
  const int rbase = blockIdx.x * 128;

  // ---- stage Wt[c][k] = bf16(W[k][c]), dword-packed (k even|odd), swizzled ----
  {
    int c = tid & 127;
    int half = tid >> 7;
#pragma unroll 4
    for (int j = 0; j < 32; j++) {
      int p = j * 2 + half;        // dword index within column = k/2
      int k = p * 2;
      float w0 = W[k * 128 + c];
      float w1 = W[(k + 1) * 128 + c];
      unsigned int packed = (unsigned int)f2bf(w0) | ((unsigned int)f2bf(w1) << 16);
      wt[(64 * c + p) ^ ((c & 7) << 2)] = packed;
    }
  }

  const int wave = tid >> 6;
  const int lane = tid & 63;
  const int l15 = lane & 15;
  const int kg = lane >> 4;  // 0..3

  // bias per col-tile; dinv per owned row
  float bcol[8];
#pragma unroll
  for (int ct = 0; ct < 8; ct++) bcol[ct] = bias[ct * 16 + l15];
  float dv[8];
#pragma unroll
  for (int rt = 0; rt < 2; rt++)
#pragma unroll
    for (int i = 0; i < 4; i++) {
      int gr = rbase + wave * 32 + rt * 16 + kg * 4 + i;
      dv[rt * 4 + i] = (gr < nrows) ? dinv[gr] : 0.f;
    }

  __syncthreads();

  f32x4 acc[2][8];
#pragma unroll
  for (int rt = 0; rt < 2; rt++)
#pragma unroll
    for (int ct = 0; ct < 8; ct++) acc[rt][ct] = (f32x4)(0.f);

#pragma unroll
  for (int ks = 0; ks < 4; ks++) {
    int kcol = ks * 32 + kg * 8;
    short8_t a[2];
#pragma unroll
    for (int rt = 0; rt < 2; rt++) {
      int row = rbase + wave * 32 + rt * 16 + l15;
      if (row < nrows) {
        const float4* xr = reinterpret_cast<const float4*>(x + (size_t)row * 128 + kcol);
        float4 v0 = xr[0], v1 = xr[1];
        a[rt][0] = (short)f2bf(v0.x); a[rt][1] = (short)f2bf(v0.y);
        a[rt][2] = (short)f2bf(v0.z); a[rt][3] = (short)f2bf(v0.w);
        a[rt][4] = (short)f2bf(v1.x); a[rt][5] = (short)f2bf(v1.y);
        a[rt][6] = (short)f2bf(v1.z); a[rt][7] = (short)f2bf(v1.w);
      } else {
#pragma unroll
        for (int e = 0; e < 8; e++) a[rt][e] = 0;
      }
    }
#pragma unroll
    for (int ct = 0; ct < 8; ct++) {
      int col = ct * 16 + l15;
      int dw0 = (64 * col + ks * 16 + kg * 4) ^ ((col & 7) << 2);
      short8_t b = *reinterpret_cast<const short8_t*>(&wt[dw0]);
      acc[0][ct] = __builtin_amdgcn_mfma_f32_16x16x32_bf16(a[0], b, acc[0][ct], 0, 0, 0);
      acc[1][ct] = __builtin_amdgcn_mfma_f32_16x16x32_bf16(a[1], b, acc[1][ct], 0, 0, 0);
    }
  }

  // epilogue: C/D layout col=lane&15, row=(lane>>4)*4+reg
#pragma unroll
  for (int rt = 0; rt < 2; rt++)
#pragma unroll
    for (int ct = 0; ct < 8; ct++)
#pragma unroll
      for (int i = 0; i < 4; i++) {
        int gr = rbase + wave * 32 + rt * 16 + kg * 4 + i;
        if (gr < nrows)
          out[(size_t)gr * 128 + ct * 16 + l15] =
              f2bf((acc[rt][ct][i] + bcol[ct]) * dv[rt * 4 + i]);
      }
}

// ================= Linear f32 (frag MLP, small) =================
template<int IC, int OC, bool RELU, int RPT>
__global__ void __launch_bounds__(256) linear_k(
    const float* __restrict__ in, const float* __restrict__ W,
    const float* __restrict__ bias, float* __restrict__ out, int nrows) {
  constexpr int GROUPS = 256 / OC;
  constexpr int RBLK = RPT * GROUPS;
  __shared__ float xs[RBLK * IC];
  const int tid = threadIdx.x;
  const int c = tid % OC;
  const int g = tid / OC;
  const int rbase = blockIdx.x * RBLK;

  constexpr int NV = RBLK * IC / 4;
  const float4* in4 = reinterpret_cast<const float4*>(in);
  for (int idx = tid; idx < NV; idx += 256) {
    int r = idx / (IC / 4);
    int kk = idx % (IC / 4);
    int gr = rbase + r;
    float4 v = make_float4(0.f, 0.f, 0.f, 0.f);
    if (gr < nrows) v = in4[(size_t)gr * (IC / 4) + kk];
    reinterpret_cast<float4*>(xs)[idx] = v;
  }
  __syncthreads();

  float acc[RPT];
  float b = bias[c];
#pragma unroll
  for (int m = 0; m < RPT; m++) acc[m] = b;

#pragma unroll 4
  for (int k = 0; k < IC; k++) {
    float w = W[k * OC + c];
#pragma unroll
    for (int m = 0; m < RPT; m++)
      acc[m] += xs[(g + m * GROUPS) * IC + k] * w;
  }

#pragma unroll
  for (int m = 0; m < RPT; m++) {
    int gr = rbase + g + m * GROUPS;
    if (gr < nrows) {
      float v = acc[m];
      if (RELU) v = fmaxf(v, 0.f);
      out[(size_t)gr * OC + c] = v;
    }
  }
}

// ================= counts (fused, with rank recording) =================
__global__ void __launch_bounds__(256) counts_k(
    const int* __restrict__ esrc, const int* __restrict__ etgt, int E,
    const int* __restrict__ a2f, int N,
    const int* __restrict__ ftgt, int FE,
    int* __restrict__ cnt_src, int* __restrict__ cnt_tgt,
    int* __restrict__ cnt_a2f, int* __restrict__ cnt_fe,
    int* __restrict__ rank_tgt, int* __restrict__ rank_a2f,
    int* __restrict__ rank_fe) {
  int i = blockIdx.x * 256 + threadIdx.x;
  if (i < E) {
    atomicAdd(&cnt_src[esrc[i]], 1);
    rank_tgt[i] = atomicAdd(&cnt_tgt[etgt[i]], 1);
  } else if (i < E + N) {
    int j = i - E;
    rank_a2f[j] = atomicAdd(&cnt_a2f[a2f[j]], 1);
  } else if (i < E + N + FE) {
    int e = i - E - N;
    rank_fe[e] = atomicAdd(&cnt_fe[ftgt[e]], 1);
  }
}

// ================= scans =================
constexpr int SCAN_C = 1024;

__global__ void __launch_bounds__(256) scan_bsum_k(const int* __restrict__ in, int n,
                                                   int* __restrict__ bsums) {
  __shared__ int s[256];
  int t = threadIdx.x;
  int base = blockIdx.x * SCAN_C;
  int v = 0;
  for (int i = t; i < SCAN_C; i += 256) {
    int g = base + i;
    if (g < n) v += in[g];
  }
  s[t] = v;
  __syncthreads();
  for (int d = 128; d > 0; d >>= 1) {
    if (t < d) s[t] += s[t + d];
    __syncthreads();
  }
  if (t == 0) bsums[blockIdx.x] = s[0];
}

__global__ void __launch_bounds__(1024) scan_small_k(int* __restrict__ bsums, int nb) {
  __shared__ int s[1024];
  int t = threadIdx.x;
  int v = (t < nb) ? bsums[t] : 0;
  s[t] = v;
  __syncthreads();
  for (int d = 1; d < 1024; d <<= 1) {
    int u = (t >= d) ? s[t - d] : 0;
    __syncthreads();
    s[t] += u;
    __syncthreads();
  }
  if (t < nb) bsums[t] = s[t] - v;  // exclusive
}

// exclusive scan of cnt_tgt -> off_tgt, plus dinv = rsqrt(cnt_src+1)
__global__ void __launch_bounds__(256) scan_final_dinv_k(
    const int* __restrict__ in, int n, const int* __restrict__ bsums,
    int* __restrict__ off, const int* __restrict__ cnt_src,
    float* __restrict__ dinv) {
  __shared__ int s[256];
  int t = threadIdx.x;
  int base = blockIdx.x * SCAN_C + t * 4;
  int a0 = (base + 0 < n) ? in[base + 0] : 0;
  int a1 = (base + 1 < n) ? in[base + 1] : 0;
  int a2 = (base + 2 < n) ? in[base + 2] : 0;
  int a3 = (base + 3 < n) ? in[base + 3] : 0;
  int tot = a0 + a1 + a2 + a3;
  s[t] = tot;
  __syncthreads();
  for (int d = 1; d < 256; d <<= 1) {
    int u = (t >= d) ? s[t - d] : 0;
    __syncthreads();
    s[t] += u;
    __syncthreads();
  }
  int pre = s[t] - tot + bsums[blockIdx.x];
  int e0 = pre, e1 = pre + a0, e2 = e1 + a1, e3 = e2 + a2;
  if (base + 0 < n) { off[base + 0] = e0; dinv[base + 0] = rsqrtf((float)(cnt_src[base + 0] + 1)); }
  if (base + 1 < n) { off[base + 1] = e1; dinv[base + 1] = rsqrtf((float)(cnt_src[base + 1] + 1)); }
  if (base + 2 < n) { off[base + 2] = e2; dinv[base + 2] = rsqrtf((float)(cnt_src[base + 2] + 1)); }
  if (base + 3 < n) { off[base + 3] = e3; dinv[base + 3] = rsqrtf((float)(cnt_src[base + 3] + 1)); }
}

// two small exclusive scans (one block each)
__global__ void __launch_bounds__(1024) scan2_k(
    const int* __restrict__ in0, int n0, int* __restrict__ off0,
    const int* __restrict__ in1, int n1, int* __restrict__ off1) {
  __shared__ int s[1024];
  const int* in = blockIdx.x == 0 ? in0 : in1;
  int n = blockIdx.x == 0 ? n0 : n1;
  int* off = blockIdx.x == 0 ? off0 : off1;
  int t = threadIdx.x;
  int carry = 0;
  for (int base = 0; base < n; base += 1024) {
    int v = (base + t < n) ? in[base + t] : 0;
    __syncthreads();
    s[t] = v;
    __syncthreads();
    for (int d = 1; d < 1024; d <<= 1) {
      int u = (t >= d) ? s[t - d] : 0;
      __syncthreads();
      s[t] += u;
      __syncthreads();
    }
    int tot = s[1023];
    if (base + t < n) off[base + t] = s[t] - v + carry;
    carry += tot;
  }
}

// ================= fill (no atomics: rank precomputed) =================
__global__ void __launch_bounds__(256) fill_k(
    const int* __restrict__ esrc, const int* __restrict__ etgt, int E,
    const int* __restrict__ a2f, int N,
    const int* __restrict__ fsrc, const int* __restrict__ ftgt, int FE,
    const int* __restrict__ off_tgt, const int* __restrict__ rank_tgt,
    const int* __restrict__ off_a2f, const int* __restrict__ rank_a2f,
    const int* __restrict__ off_fe, const int* __restrict__ rank_fe,
    int* __restrict__ csr_src, int* __restrict__ aids, int* __restrict__ csr_fs) {
  int i = blockIdx.x * 256 + threadIdx.x;
  if (i < E) {
    csr_src[off_tgt[etgt[i]] + rank_tgt[i]] = esrc[i];
  } else if (i < E + N) {
    int j = i - E;
    aids[off_a2f[a2f[j]] + rank_a2f[j]] = j;
  } else if (i < E + N + FE) {
    int e = i - E - N;
    csr_fs[off_fe[ftgt[e]] + rank_fe[e]] = fsrc[e];
  }
}

// ================= gathers =================
// out[t] = dinv[t] * (h'[t] + sum_{s in csr(t)} h'[s]) ; h' bf16
__global__ void __launch_bounds__(256) edge_gather_k(
    const int* __restrict__ off, const int* __restrict__ cnt,
    const int* __restrict__ csr_src, const unsigned short* __restrict__ h,
    const float* __restrict__ dinv, float* __restrict__ out, int n) {
  int tn = blockIdx.x * 8 + (threadIdx.x >> 5);
  if (tn >= n) return;
  int lane = threadIdx.x & 31;
  const ushort4* h4 = reinterpret_cast<const ushort4*>(h);
  ushort4 hv = h4[(size_t)tn * 32 + lane];
  float ax = bf2f(hv.x), ay = bf2f(hv.y), az = bf2f(hv.z), aw = bf2f(hv.w);
  int s0 = off[tn], c = cnt[tn];
  int i = 0;
  for (; i + 4 <= c; i += 4) {
    int s1 = csr_src[s0 + i + 0];
    int s2 = csr_src[s0 + i + 1];
    int s3 = csr_src[s0 + i + 2];
    int s4 = csr_src[s0 + i + 3];
    ushort4 v1 = h4[(size_t)s1 * 32 + lane];
    ushort4 v2 = h4[(size_t)s2 * 32 + lane];
    ushort4 v3 = h4[(size_t)s3 * 32 + lane];
    ushort4 v4 = h4[(size_t)s4 * 32 + lane];
    ax += (bf2f(v1.x) + bf2f(v2.x)) + (bf2f(v3.x) + bf2f(v4.x));
    ay += (bf2f(v1.y) + bf2f(v2.y)) + (bf2f(v3.y) + bf2f(v4.y));
    az += (bf2f(v1.z) + bf2f(v2.z)) + (bf2f(v3.z) + bf2f(v4.z));
    aw += (bf2f(v1.w) + bf2f(v2.w)) + (bf2f(v3.w) + bf2f(v4.w));
  }
  for (; i < c; i++) {
    int s1 = csr_src[s0 + i];
    ushort4 v1 = h4[(size_t)s1 * 32 + lane];
    ax += bf2f(v1.x); ay += bf2f(v1.y); az += bf2f(v1.z); aw += bf2f(v1.w);
  }
  float dt = dinv[tn];
  reinterpret_cast<float4*>(out)[(size_t)tn * 32 + lane] =
      make_float4(ax * dt, ay * dt, az * dt, aw * dt);
}

// dst[f] = sum_{a in group f} src_rows[a]  (f32 rows)
__global__ void __launch_bounds__(256) seg_gather_k(
    const int* __restrict__ off, const int* __restrict__ cnt,
    const int* __restrict__ ids, const float* __restrict__ src_rows,
    float* __restrict__ dst, int n) {
  int f = blockIdx.x * 8 + (threadIdx.x >> 5);
  if (f >= n) return;
  int lane = threadIdx.x & 31;
  const float4* s4 = reinterpret_cast<const float4*>(src_rows);
  float ax = 0.f, ay = 0.f, az = 0.f, aw = 0.f;
  int s0 = off[f], c = cnt[f];
  int i = 0;
  for (; i + 2 <= c; i += 2) {
    int a1 = ids[s0 + i], a2 = ids[s0 + i + 1];
    float4 v1 = s4[(size_t)a1 * 32 + lane];
    float4 v2 = s4[(size_t)a2 * 32 + lane];
    ax += v1.x + v2.x; ay += v1.y + v2.y; az += v1.z + v2.z; aw += v1.w + v2.w;
  }
  if (i < c) {
    int a1 = ids[s0 + i];
    float4 v1 = s4[(size_t)a1 * 32 + lane];
    ax += v1.x; ay += v1.y; az += v1.z; aw += v1.w;
  }
  reinterpret_cast<float4*>(dst)[(size_t)f * 32 + lane] = make_float4(ax, ay, az, aw);
}

// ================= launch =================
extern "C" void kernel_launch(void* const* d_in, const int* in_sizes, int n_in,
                              void* d_out, int out_size, void* d_ws, size_t ws_size,
                              hipStream_t stream) {
  const float* x_atoms    = (const float*)d_in[0];
  const int*   edge_index = (const int*)d_in[1];
  // d_in[2] edge_attr: dead in reference — never read.
  const int*   frag_index = (const int*)d_in[3];
  // d_in[4] x_frags: values unused.
  const int*   a2f     = (const int*)d_in[5];
  const float* atom_w  = (const float*)d_in[6];
  const float* atom_b  = (const float*)d_in[7];
  // d_in[8..9] edge_w/edge_b: unused.
  const float* frag_w1 = (const float*)d_in[10];
  const float* frag_b1 = (const float*)d_in[11];
  const float* frag_w2 = (const float*)d_in[12];
  const float* frag_b2 = (const float*)d_in[13];

  const int N  = in_sizes[0] / DD;   // 100000
  const int E  = in_sizes[1] / 2;    // 1600000
  const int FE = in_sizes[3] / 2;    // 80000
  const int NF = in_sizes[4] / DD;   // 10000

  const int* esrc = edge_index;
  const int* etgt = edge_index + E;
  const int* fsrc = frag_index;
  const int* ftgt = frag_index + FE;

  float* out_atoms = (float*)d_out;
  float* out_frags = out_atoms + (size_t)N * DD;

  char* ws = (char*)d_ws;
  size_t off_b = 0;
  auto alloc = [&](size_t bytes) {
    void* p = ws + off_b;
    off_b += (bytes + 255) & ~(size_t)255;
    return p;
  };
  unsigned short* h = (unsigned short*)alloc((size_t)N * DD * 2);  // 25.6 MB bf16
  float* dinv     = (float*)alloc((size_t)N * 4);
  int*   cnts     = (int*)alloc(((size_t)2 * N + 2 * NF) * 4);  // one zeroed block
  int*   cnt_src  = cnts;
  int*   cnt_tgt  = cnts + N;
  int*   cnt_a2f  = cnts + 2 * N;
  int*   cnt_fe   = cnts + 2 * N + NF;
  int*   off_tgt  = (int*)alloc((size_t)N * 4);
  int*   rank_tgt = (int*)alloc((size_t)E * 4);
  int*   csr_src  = (int*)alloc((size_t)E * 4);
  int*   off_a2f  = (int*)alloc((size_t)NF * 4);
  int*   rank_a2f = (int*)alloc((size_t)N * 4);
  int*   aids     = (int*)alloc((size_t)N * 4);
  int*   off_fe   = (int*)alloc((size_t)NF * 4);
  int*   rank_fe  = (int*)alloc((size_t)FE * 4);
  int*   csr_fs   = (int*)alloc((size_t)FE * 4);
  int*   bsums    = (int*)alloc(1024 * 4);
  float* ff       = (float*)alloc((size_t)NF * DD * 4);
  float* fs       = (float*)alloc((size_t)NF * DD * 4);
  float* hid      = (float*)alloc((size_t)NF * 2 * DD * 4);

  hipMemsetAsync(cnts, 0, ((size_t)2 * N + 2 * NF) * 4, stream);

  // counts + ranks (the only atomic pass)
  counts_k<<<(E + N + FE + 255) / 256, 256, 0, stream>>>(
      esrc, etgt, E, a2f, N, ftgt, FE,
      cnt_src, cnt_tgt, cnt_a2f, cnt_fe, rank_tgt, rank_a2f, rank_fe);

  // scans (+ dinv fused into the big one)
  int nb1 = (N + SCAN_C - 1) / SCAN_C;
  scan_bsum_k<<<nb1, 256, 0, stream>>>(cnt_tgt, N, bsums);
  scan_small_k<<<1, 1024, 0, stream>>>(bsums, nb1);
  scan_final_dinv_k<<<nb1, 256, 0, stream>>>(cnt_tgt, N, bsums, off_tgt, cnt_src, dinv);
  scan2_k<<<2, 1024, 0, stream>>>(cnt_a2f, NF, off_a2f, cnt_fe, NF, off_fe);

  // fills (atomic-free)
  fill_k<<<(E + N + FE + 255) / 256, 256, 0, stream>>>(
      esrc, etgt, E, a2f, N, fsrc, ftgt, FE,
      off_tgt, rank_tgt, off_a2f, rank_a2f, off_fe, rank_fe,
      csr_src, aids, csr_fs);

  // h' = (x @ W + b) * dinv  (bf16, MFMA)
  mfma_h_k<<<(N + 127) / 128, 256, 0, stream>>>(x_atoms, atom_w, atom_b, dinv, h, N);

  // gathers
  edge_gather_k<<<(N + 7) / 8, 256, 0, stream>>>(off_tgt, cnt_tgt, csr_src, h, dinv, out_atoms, N);
  seg_gather_k<<<(NF + 7) / 8, 256, 0, stream>>>(off_a2f, cnt_a2f, aids, out_atoms, ff, NF);
  seg_gather_k<<<(NF + 7) / 8, 256, 0, stream>>>(off_fe, cnt_fe, csr_fs, ff, fs, NF);

  // MLP (f32)
  linear_k<128, 256, true, 32><<<(NF + 31) / 32, 256, 0, stream>>>(fs, frag_w1, frag_b1, hid, NF);
  linear_k<256, 128, false, 16><<<(NF + 31) / 32, 256, 0, stream>>>(hid, frag_w2, frag_b2, out_frags, NF);
}